// Round 9
// baseline (155.678 us; speedup 1.0000x reference)
//
#include <hip/hip_runtime.h>
#include <hip/hip_bf16.h>

// Problem constants
#define Bv 4
#define Sv 4096
#define Dv 1024
#define Hv 16
#define Ov 64
#define NCv 64
#define BHv 64

typedef __attribute__((ext_vector_type(8))) short bf16x8;
typedef __attribute__((ext_vector_type(4))) unsigned short u16x4;
typedef __attribute__((ext_vector_type(8))) unsigned short u16x8;
typedef __attribute__((ext_vector_type(4))) float f32x4;
#define MFMA(a, b, c) __builtin_amdgcn_mfma_f32_16x16x32_bf16(a, b, c, 0, 0, 0)

__device__ __forceinline__ unsigned short f2bs(float f) {
  union { __hip_bfloat16 h; unsigned short u; } v;
  v.h = __float2bfloat16(f);
  return v.u;
}
__device__ __forceinline__ float b2f(unsigned short u) {
  union { unsigned u; float f; } v; v.u = ((unsigned)u) << 16; return v.f;
}
__device__ __forceinline__ float elu1(float a) {
  return a > 0.f ? a + 1.f : __expf(a);
}
__device__ __forceinline__ f32x4 zero4() {
  f32x4 v = {0.f, 0.f, 0.f, 0.f}; return v;
}
__device__ __forceinline__ bf16x8 pack8(float4 a, float4 b) {
  union { u16x8 u; bf16x8 h; } r;
  r.u[0] = f2bs(a.x); r.u[1] = f2bs(a.y); r.u[2] = f2bs(a.z); r.u[3] = f2bs(a.w);
  r.u[4] = f2bs(b.x); r.u[5] = f2bs(b.y); r.u[6] = f2bs(b.z); r.u[7] = f2bs(b.w);
  return r.h;
}

// ---------------------------------------------------------------------------
// K0 prep: Wq/Wk/Wv [h][d][o] -> bf16 [h][o][d]; Wp [d][o2] -> bf16 [o2][d]
// ---------------------------------------------------------------------------
__global__ __launch_bounds__(256) void k_prep_w(
    const float* __restrict__ Wq, const float* __restrict__ Wk,
    const float* __restrict__ Wv, const float* __restrict__ Wp,
    unsigned short* __restrict__ wqT, unsigned short* __restrict__ wkT,
    unsigned short* __restrict__ wvT, unsigned short* __restrict__ wpT)
{
  const int blk = blockIdx.x, tid = threadIdx.x;
  if (blk < 16) {
    int h = blk;
    for (int j = tid; j < 4096; j += 256) {       // j = o*64 + d (output idx)
      int o = j >> 6, d = j & 63;
      int src = h * 4096 + d * 64 + o;
      wqT[h * 4096 + j] = f2bs(Wq[src]);
      wkT[h * 4096 + j] = f2bs(Wk[src]);
      wvT[h * 4096 + j] = f2bs(Wv[src]);
    }
  } else {
    int b2 = blk - 16;
#pragma unroll
    for (int k = 0; k < 4; ++k) {
      int j = b2 * 1024 + tid + k * 256;          // j = o2*1024 + d
      int o = j >> 10, d = j & 1023;
      wpT[j] = f2bs(Wp[d * 64 + o]);
    }
  }
}

// ---------------------------------------------------------------------------
// K1: per (bh,chunk): K=elu1(x Wk), V=x Wv
//   publishes ONLY: mir [o][e] = (K^T V)^T bf16, zmir [e] bf16  (34 MB total)
// ---------------------------------------------------------------------------
__global__ __launch_bounds__(256) void k_chunk_state(
    const float* __restrict__ x, const unsigned short* __restrict__ wkT,
    const unsigned short* __restrict__ wvT, unsigned short* __restrict__ mir,
    unsigned short* __restrict__ zmir)
{
  __shared__ __align__(16) unsigned short kT[64][72];     // K^T[e][t]
  __shared__ __align__(16) unsigned short vT[64][72];     // V^T[o][t]
  __shared__ float zpart[4][64];

  const int tid = threadIdx.x, blk = blockIdx.x;
  const int c = blk & 63, bh = blk >> 6, h = bh & 15, b = bh >> 4;
  const int lane = tid & 63, w = tid >> 6;
  const int ll = lane & 15, hl = lane >> 4;

  const float* xr = x + ((size_t)(b * Sv + c * 64 + w * 16 + ll)) * 1024 + h * 64;
  float4 f0 = *(const float4*)(xr + hl * 8);
  float4 f1 = *(const float4*)(xr + hl * 8 + 4);
  float4 f2 = *(const float4*)(xr + 32 + hl * 8);
  float4 f3 = *(const float4*)(xr + 32 + hl * 8 + 4);
  const bf16x8 xa0 = pack8(f0, f1);
  const bf16x8 xa1 = pack8(f2, f3);

  // K = elu1(x Wk) -> kT + zpart
  const unsigned short* wk = wkT + h * 4096;
#pragma unroll
  for (int ct = 0; ct < 4; ++ct) {
    bf16x8 b0 = *(const bf16x8*)(wk + (ct * 16 + ll) * 64 + hl * 8);
    bf16x8 b1 = *(const bf16x8*)(wk + (ct * 16 + ll) * 64 + 32 + hl * 8);
    f32x4 a = zero4(); a = MFMA(xa0, b0, a); a = MFMA(xa1, b1, a);
    u16x4 p; float part = 0.f;
#pragma unroll
    for (int r = 0; r < 4; ++r) {
      float kv = elu1(a[r]); part += kv;
      p[r] = f2bs(kv);
    }
    *(u16x4*)&kT[ct * 16 + ll][w * 16 + hl * 4] = p;
    part += __shfl_xor(part, 16);
    part += __shfl_xor(part, 32);
    if (hl == 0) zpart[w][ct * 16 + ll] = part;
  }
  // V = x Wv -> vT[o][t]
  const unsigned short* wv = wvT + h * 4096;
#pragma unroll
  for (int ct = 0; ct < 4; ++ct) {
    bf16x8 b0 = *(const bf16x8*)(wv + (ct * 16 + ll) * 64 + hl * 8);
    bf16x8 b1 = *(const bf16x8*)(wv + (ct * 16 + ll) * 64 + 32 + hl * 8);
    f32x4 a = zero4(); a = MFMA(xa0, b0, a); a = MFMA(xa1, b1, a);
    u16x4 p;
#pragma unroll
    for (int r = 0; r < 4; ++r) p[r] = f2bs(a[r]);
    *(u16x4*)&vT[ct * 16 + ll][w * 16 + hl * 4] = p;
  }
  __syncthreads();

  // KtV: C[e][o]; write transposed [o][e] to mir
  const bf16x8 ka0 = *(const bf16x8*)&kT[w * 16 + ll][hl * 8];
  const bf16x8 ka1 = *(const bf16x8*)&kT[w * 16 + ll][32 + hl * 8];
  unsigned short* mp = mir + (size_t)blk * 4096;
#pragma unroll
  for (int ct = 0; ct < 4; ++ct) {
    bf16x8 v0 = *(const bf16x8*)&vT[ct * 16 + ll][hl * 8];
    bf16x8 v1 = *(const bf16x8*)&vT[ct * 16 + ll][32 + hl * 8];
    f32x4 s = zero4(); s = MFMA(ka0, v0, s); s = MFMA(ka1, v1, s);
    u16x4 p;
#pragma unroll
    for (int r = 0; r < 4; ++r) p[r] = f2bs(s[r]);
    *(u16x4*)&mp[(ct * 16 + ll) * 64 + w * 16 + hl * 4] = p;
  }
  if (tid < 64)
    zmir[(size_t)blk * 64 + tid] = f2bs(
        zpart[0][tid] + zpart[1][tid] + zpart[2][tid] + zpart[3][tid]);
}

// ---------------------------------------------------------------------------
// K2: exclusive prefix over chunks — loads up-front, register scan, stores.
// ---------------------------------------------------------------------------
__global__ __launch_bounds__(256) void k_prefix(
    unsigned short* __restrict__ mir, unsigned short* __restrict__ zmir)
{
  const int bh = blockIdx.x / 17, g = blockIdx.x % 17;
  const int tid = threadIdx.x;
  if (g < 16) {
    size_t base = (size_t)bh * 64 * 4096 + g * 256 + tid;
    unsigned short v[64];
#pragma unroll
    for (int cc = 0; cc < 64; ++cc) v[cc] = mir[base + (size_t)cc * 4096];
    float carry = 0.f;
#pragma unroll
    for (int cc = 0; cc < 64; ++cc) {
      float f = b2f(v[cc]);
      v[cc] = f2bs(carry);
      carry += f;
    }
#pragma unroll
    for (int cc = 0; cc < 64; ++cc) mir[base + (size_t)cc * 4096] = v[cc];
  } else if (tid < 64) {
    size_t base = (size_t)bh * 64 * 64 + tid;
    unsigned short v[64];
#pragma unroll
    for (int cc = 0; cc < 64; ++cc) v[cc] = zmir[base + (size_t)cc * 64];
    float carry = 0.f;
#pragma unroll
    for (int cc = 0; cc < 64; ++cc) {
      float f = b2f(v[cc]);
      v[cc] = f2bs(carry);
      carry += f;
    }
#pragma unroll
    for (int cc = 0; cc < 64; ++cc) zmir[base + (size_t)cc * 64] = v[cc];
  }
}

// ---------------------------------------------------------------------------
// K3: per (b,chunk,4-head-group): for each of 4 heads:
//   recompute Q,K,V from x (L3-hot);  A = tril(Q K^T);
//   y_h = (Q Sprev + A V) / (q.zprev + rowsum + eps);  oacc += y_h @ Wp_h
// 2 barriers per head (K,V LDS transposes are cross-wave); qrow stripe reuse
// (Q -> A -> y -> oacc staging) is wave-private.
// ---------------------------------------------------------------------------
__global__ __launch_bounds__(256) void k_fused(
    const float* __restrict__ x, const unsigned short* __restrict__ wqT,
    const unsigned short* __restrict__ wkT, const unsigned short* __restrict__ wvT,
    const unsigned short* __restrict__ mir, const unsigned short* __restrict__ zmir,
    const unsigned short* __restrict__ wpT, unsigned short* __restrict__ partial)
{
  __shared__ __align__(16) unsigned short qrow[64][72];  // Q / A / y / out stage
  __shared__ __align__(16) unsigned short krow[64][72];  // K[s][e]
  __shared__ __align__(16) unsigned short vT[64][72];    // V^T[o][t]

  const int tid = threadIdx.x, bid = blockIdx.x;
  const int g = bid & 3, c = (bid >> 2) & 63, b = bid >> 8;
  const int lane = tid & 63, w = tid >> 6;
  const int ll = lane & 15, hl = lane >> 4;

  f32x4 oacc[4] = {zero4(), zero4(), zero4(), zero4()};

#pragma unroll 1
  for (int hi = 0; hi < 4; ++hi) {
    const int h = g * 4 + hi;
    const size_t sblk = (size_t)((b * 16 + h) * 64 + c);
    if (hi) __syncthreads();   // protect krow/vT reuse across heads

    // x slice (L3-hot second read)
    const float* xr = x + ((size_t)(b * Sv + c * 64 + w * 16 + ll)) * 1024 + h * 64;
    float4 f0 = *(const float4*)(xr + hl * 8);
    float4 f1 = *(const float4*)(xr + hl * 8 + 4);
    float4 f2 = *(const float4*)(xr + 32 + hl * 8);
    float4 f3 = *(const float4*)(xr + 32 + hl * 8 + 4);
    const bf16x8 xa0 = pack8(f0, f1);
    const bf16x8 xa1 = pack8(f2, f3);

    // Q ladder -> qrow[t][e]
    const unsigned short* wq = wqT + h * 4096;
#pragma unroll
    for (int ct = 0; ct < 4; ++ct) {
      bf16x8 b0 = *(const bf16x8*)(wq + (ct * 16 + ll) * 64 + hl * 8);
      bf16x8 b1 = *(const bf16x8*)(wq + (ct * 16 + ll) * 64 + 32 + hl * 8);
      f32x4 a = zero4(); a = MFMA(xa0, b0, a); a = MFMA(xa1, b1, a);
#pragma unroll
      for (int r = 0; r < 4; ++r)
        qrow[w * 16 + hl * 4 + r][ct * 16 + ll] = f2bs(elu1(a[r]));
    }
    // K ladder -> krow[s][e]
    const unsigned short* wk = wkT + h * 4096;
#pragma unroll
    for (int ct = 0; ct < 4; ++ct) {
      bf16x8 b0 = *(const bf16x8*)(wk + (ct * 16 + ll) * 64 + hl * 8);
      bf16x8 b1 = *(const bf16x8*)(wk + (ct * 16 + ll) * 64 + 32 + hl * 8);
      f32x4 a = zero4(); a = MFMA(xa0, b0, a); a = MFMA(xa1, b1, a);
#pragma unroll
      for (int r = 0; r < 4; ++r)
        krow[w * 16 + hl * 4 + r][ct * 16 + ll] = f2bs(elu1(a[r]));
    }
    // V ladder -> vT[o][t]
    const unsigned short* wv = wvT + h * 4096;
#pragma unroll
    for (int ct = 0; ct < 4; ++ct) {
      bf16x8 b0 = *(const bf16x8*)(wv + (ct * 16 + ll) * 64 + hl * 8);
      bf16x8 b1 = *(const bf16x8*)(wv + (ct * 16 + ll) * 64 + 32 + hl * 8);
      f32x4 a = zero4(); a = MFMA(xa0, b0, a); a = MFMA(xa1, b1, a);
      u16x4 p;
#pragma unroll
      for (int r = 0; r < 4; ++r) p[r] = f2bs(a[r]);
      *(u16x4*)&vT[ct * 16 + ll][w * 16 + hl * 4] = p;
    }
    __syncthreads();   // krow/vT visible to all waves

    const bf16x8 qa0 = *(const bf16x8*)&qrow[w * 16 + ll][hl * 8];
    const bf16x8 qa1 = *(const bf16x8*)&qrow[w * 16 + ll][32 + hl * 8];

    // den0 = q . zprev
    const unsigned short* zp = zmir + sblk * 64;
    u16x8 zz0 = *(const u16x8*)(zp + hl * 8);
    u16x8 zz1 = *(const u16x8*)(zp + 32 + hl * 8);
    const u16x8 qu0 = *(const u16x8*)&qa0;
    const u16x8 qu1 = *(const u16x8*)&qa1;
    float den0 = 0.f;
#pragma unroll
    for (int i = 0; i < 8; ++i) {
      den0 += b2f(qu0[i]) * b2f(zz0[i]);
      den0 += b2f(qu1[i]) * b2f(zz1[i]);
    }
    den0 += __shfl_xor(den0, 16);
    den0 += __shfl_xor(den0, 32);

    // A = tril(Q K^T) from LDS krow
    f32x4 aacc[4];
#pragma unroll
    for (int ct = 0; ct < 4; ++ct) {
      if (ct <= w) {   // wave-uniform
        bf16x8 b0 = *(const bf16x8*)&krow[ct * 16 + ll][hl * 8];
        bf16x8 b1 = *(const bf16x8*)&krow[ct * 16 + ll][32 + hl * 8];
        f32x4 a = zero4(); a = MFMA(qa0, b0, a); a = MFMA(qa1, b1, a);
        if (ct == w) {  // causal mask, static indices
#pragma unroll
          for (int r = 0; r < 4; ++r)
            if (ll > hl * 4 + r) a[r] = 0.f;
        }
        aacc[ct] = a;
      } else {
        aacc[ct] = zero4();
      }
    }
    float denA[4];
#pragma unroll
    for (int r = 0; r < 4; ++r)
      denA[r] = aacc[0][r] + aacc[1][r] + aacc[2][r] + aacc[3][r];
#pragma unroll
    for (int m = 1; m <= 8; m <<= 1)
#pragma unroll
      for (int r = 0; r < 4; ++r) denA[r] += __shfl_xor(denA[r], m);
    float inv[4];
#pragma unroll
    for (int r = 0; r < 4; ++r)
      inv[r] = 1.f / (__shfl(den0, hl * 4 + r) + denA[r] + 1e-6f);

    // A transpose via qrow (own stripe; Q already consumed)
#pragma unroll
    for (int ct = 0; ct < 4; ++ct)
#pragma unroll
      for (int r = 0; r < 4; ++r)
        qrow[w * 16 + hl * 4 + r][ct * 16 + ll] = f2bs(aacc[ct][r]);
    const bf16x8 aa0 = *(const bf16x8*)&qrow[w * 16 + ll][hl * 8];
    const bf16x8 aa1 = *(const bf16x8*)&qrow[w * 16 + ll][32 + hl * 8];

    // num = Q Sprev (mir, global) + A V (vT, LDS)
    const unsigned short* sp = mir + sblk * 4096;
    f32x4 nacc[4];
#pragma unroll
    for (int ct = 0; ct < 4; ++ct) {
      bf16x8 s0 = *(const bf16x8*)(sp + (ct * 16 + ll) * 64 + hl * 8);
      bf16x8 s1 = *(const bf16x8*)(sp + (ct * 16 + ll) * 64 + 32 + hl * 8);
      f32x4 a = zero4(); a = MFMA(qa0, s0, a); a = MFMA(qa1, s1, a);
      bf16x8 v0 = *(const bf16x8*)&vT[ct * 16 + ll][hl * 8];
      a = MFMA(aa0, v0, a);
      if (w >= 2) {
        bf16x8 v1 = *(const bf16x8*)&vT[ct * 16 + ll][32 + hl * 8];
        a = MFMA(aa1, v1, a);
      }
      nacc[ct] = a;
    }

    // y transpose via qrow (own stripe)
#pragma unroll
    for (int ct = 0; ct < 4; ++ct)
#pragma unroll
      for (int r = 0; r < 4; ++r)
        qrow[w * 16 + hl * 4 + r][ct * 16 + ll] = f2bs(nacc[ct][r] * inv[r]);
    const bf16x8 ya0 = *(const bf16x8*)&qrow[w * 16 + ll][hl * 8];
    const bf16x8 ya1 = *(const bf16x8*)&qrow[w * 16 + ll][32 + hl * 8];

    // oacc += y_h @ Wp_h
#pragma unroll
    for (int ct = 0; ct < 4; ++ct) {
      const unsigned short* wpr = wpT + (size_t)(ct * 16 + ll) * 1024 + h * 64;
      bf16x8 w0 = *(const bf16x8*)(wpr + hl * 8);
      bf16x8 w1 = *(const bf16x8*)(wpr + 32 + hl * 8);
      oacc[ct] = MFMA(ya0, w0, oacc[ct]);
      oacc[ct] = MFMA(ya1, w1, oacc[ct]);
    }
  }

  // stage + coalesced bf16 partial store (wave-private rows both sides)
#pragma unroll
  for (int ct = 0; ct < 4; ++ct)
#pragma unroll
    for (int r = 0; r < 4; ++r)
      qrow[w * 16 + hl * 4 + r][ct * 16 + ll] = f2bs(oacc[ct][r]);
  unsigned short* pp = partial + (size_t)g * 1048576 +
                       ((size_t)(b * Sv + c * 64)) * 64;
  {
    int r_ = tid >> 2, c_ = (tid & 3) * 16;   // tid/4 stays in own wave stripe
    uint4 q0 = *(const uint4*)&qrow[r_][c_];
    uint4 q1 = *(const uint4*)&qrow[r_][c_ + 8];
    *(uint4*)&pp[r_ * 64 + c_] = q0;
    *(uint4*)&pp[r_ * 64 + c_ + 8] = q1;
  }
}

// ---------------------------------------------------------------------------
// K4: out = sum_g partial[g]  (bf16 -> f32), 4 groups
// ---------------------------------------------------------------------------
__global__ __launch_bounds__(256) void k_add(
    const unsigned short* __restrict__ partial, float* __restrict__ out)
{
  const int idx = (blockIdx.x * 256 + threadIdx.x) * 8;
  float acc[8] = {0.f, 0.f, 0.f, 0.f, 0.f, 0.f, 0.f, 0.f};
#pragma unroll
  for (int g = 0; g < 4; ++g) {
    u16x8 p = *(const u16x8*)(partial + (size_t)g * 1048576 + idx);
#pragma unroll
    for (int j = 0; j < 8; ++j) acc[j] += b2f(p[j]);
  }
  float4 r0 = {acc[0], acc[1], acc[2], acc[3]};
  float4 r1 = {acc[4], acc[5], acc[6], acc[7]};
  *(float4*)(out + idx) = r0;
  *(float4*)(out + idx + 4) = r1;
}

// ---------------------------------------------------------------------------
extern "C" void kernel_launch(void* const* d_in, const int* in_sizes, int n_in,
                              void* d_out, int out_size, void* d_ws, size_t ws_size,
                              hipStream_t stream)
{
  const float* x  = (const float*)d_in[0];
  const float* Wq = (const float*)d_in[1];
  const float* Wk = (const float*)d_in[2];
  const float* Wv = (const float*)d_in[3];
  const float* Wp = (const float*)d_in[4];
  float* out = (float*)d_out;

  // ws layout: mir bf16 33.55 MB | zmir bf16 0.52 | wqT/wkT/wvT/wpT 0.52 |
  //            partial bf16 [4][16384][64] 8.4 MB    (total ~43 MB)
  unsigned short* mir = (unsigned short*)d_ws;
  unsigned short* zmir = mir + 16777216;
  unsigned short* wqT = zmir + 262144;
  unsigned short* wkT = wqT + 65536;
  unsigned short* wvT = wkT + 65536;
  unsigned short* wpT = wvT + 65536;
  unsigned short* partial = wpT + 65536;

  hipLaunchKernelGGL(k_prep_w, dim3(80), dim3(256), 0, stream,
                     Wq, Wk, Wv, Wp, wqT, wkT, wvT, wpT);
  hipLaunchKernelGGL(k_chunk_state, dim3(BHv * NCv), dim3(256), 0, stream,
                     x, wkT, wvT, mir, zmir);
  hipLaunchKernelGGL(k_prefix, dim3(BHv * 17), dim3(256), 0, stream, mir, zmir);
  hipLaunchKernelGGL(k_fused, dim3(Bv * NCv * 4), dim3(256), 0, stream,
                     x, wqT, wkT, wvT, mir, zmir, wpT, partial);
  hipLaunchKernelGGL(k_add, dim3(512), dim3(256), 0, stream, partial, out);
}